// Round 11
// baseline (1363.548 us; speedup 1.0000x reference)
//
#include <hip/hip_runtime.h>
#include <cstddef>

#define HH   256   // HEADS*HID
#define OUTC 64
#define NEG  0.2f

typedef _Float16 half8  __attribute__((ext_vector_type(8)));
typedef _Float16 half4v __attribute__((ext_vector_type(4)));
typedef float    f32x4  __attribute__((ext_vector_type(4)));

// real XCD id [measured: learn_hip m09] -- s_getreg(HW_REG_XCC_ID=20, off 0, sz 32)
__device__ __forceinline__ int xcc_id() {
    return __builtin_amdgcn_s_getreg(20 | (0 << 6) | (31 << 11)) & 7;
}

// ---------------- CSR build ----------------

// histogram + folded weight transpose/casts + qctr zero
__global__ __launch_bounds__(256) void hist_cast(const int* __restrict__ ei, int E, int N,
                                                 const float* __restrict__ W1,
                                                 const float* __restrict__ W2,
                                                 _Float16* __restrict__ W1t,
                                                 _Float16* __restrict__ W2t,
                                                 int* __restrict__ deg,
                                                 int* __restrict__ qctr) {
    int i = blockIdx.x * 256 + threadIdx.x;
    if (i < 8) qctr[i] = 0;
    int tot = E + N;
    if (i < tot) {
        int dst = (i < E) ? ei[E + i] : (i - E);   // self-loop for i>=E
        atomicAdd(&deg[dst], 1);
    }
    const int n1 = 128 * HH, n2 = HH * OUTC;
    if (i < n1 + n2) {
        if (i < n1) { int nn = i / 128, k = i - nn * 128; W1t[i] = (_Float16)W1[(size_t)k * HH + nn]; }
        else { int j = i - n1; int nn = j / HH, k = j - nn * HH; W2t[j] = (_Float16)W2[(size_t)k * OUTC + nn]; }
    }
}

__global__ __launch_bounds__(256) void scan_block(const int* __restrict__ deg,
                                                  int* __restrict__ offs,
                                                  int* __restrict__ part, int n) {
    __shared__ int sh[256];
    int t = threadIdx.x;
    int i = blockIdx.x * 256 + t;
    int v = (i < n) ? deg[i] : 0;
    sh[t] = v;
    __syncthreads();
    for (int off = 1; off < 256; off <<= 1) {
        int x = (t >= off) ? sh[t - off] : 0;
        __syncthreads();
        sh[t] += x;
        __syncthreads();
    }
    if (i < n) offs[i + 1] = sh[t];
    if (t == 255) part[blockIdx.x] = sh[255];
}

// merged: each block redundantly scans part[] (nb<=256), applies prefix, writes cursor
__global__ __launch_bounds__(256) void scan_finish(int* __restrict__ offs,
                                                   int* __restrict__ cursor,
                                                   const int* __restrict__ deg,
                                                   const int* __restrict__ part,
                                                   int n, int nb) {
    __shared__ int sh[256];
    int t = threadIdx.x, bid = blockIdx.x;
    sh[t] = (t < nb) ? part[t] : 0;
    __syncthreads();
    for (int off = 1; off < 256; off <<= 1) {
        int x = (t >= off) ? sh[t - off] : 0;
        __syncthreads();
        sh[t] += x;
        __syncthreads();
    }
    int excl = (bid == 0) ? 0 : sh[bid - 1];
    int i = bid * 256 + t;
    if (i < n) {
        int v = offs[i + 1] + excl;
        offs[i + 1] = v;
        cursor[i] = v - deg[i];
    }
    if (i == 0) offs[0] = 0;
}

__global__ __launch_bounds__(256) void scatter_kernel(const int* __restrict__ ei, int E, int N,
                                                      int* __restrict__ cursor,
                                                      int* __restrict__ esrc) {
    int i = blockIdx.x * blockDim.x + threadIdx.x;
    int tot = E + N;
    if (i >= tot) return;
    int src, dst;
    if (i < E) { src = ei[i]; dst = ei[E + i]; }
    else       { src = dst = i - E; }
    int pos = atomicAdd(&cursor[dst], 1);
    esrc[pos] = src;
}

// ---------------- MFMA fp16 GEMM (swapped operands, fused score epilogue) ----------------
// Scores TRANSPOSED: asT[h*M+row] (XCD-local tables for sliced agg); ad_[row*H+h].

template <int K, int NT, int HEADS, bool AF32>
__global__ __launch_bounds__(256) void mfma_gemm(const void* __restrict__ Av,
                                                 const _Float16* __restrict__ Bt,
                                                 _Float16* __restrict__ C,
                                                 const float* __restrict__ atts,
                                                 const float* __restrict__ attd,
                                                 float* __restrict__ asT,
                                                 float* __restrict__ ad_,
                                                 int M) {
    constexpr int N = NT * 16;
    int t = threadIdx.x;
    int w = t >> 6, l = t & 63;
    int lm = l & 15, lk = l >> 4;
    int row0 = blockIdx.x * 64 + w * 16;
    int rowv = row0 + lm;
    int rA = rowv; if (rA >= M) rA = M - 1;
    int kOff = lk * 8;

    f32x4 acc[NT];
#pragma unroll
    for (int i = 0; i < NT; ++i) acc[i] = (f32x4){0.f, 0.f, 0.f, 0.f};

    const float*    Af = (const float*)Av    + (size_t)rA * K + kOff;
    const _Float16* Ah = (const _Float16*)Av + (size_t)rA * K + kOff;
    const _Float16* Bp = Bt + (size_t)lm * K + kOff;

#pragma unroll 1
    for (int ks = 0; ks < K / 32; ++ks) {
        half8 a;
        if constexpr (AF32) {
            float4 a0 = *(const float4*)(Af + ks * 32);
            float4 a1 = *(const float4*)(Af + ks * 32 + 4);
            a = (half8){(_Float16)a0.x, (_Float16)a0.y, (_Float16)a0.z, (_Float16)a0.w,
                        (_Float16)a1.x, (_Float16)a1.y, (_Float16)a1.z, (_Float16)a1.w};
        } else {
            a = *(const half8*)(Ah + ks * 32);
        }
#pragma unroll
        for (int nt = 0; nt < NT; ++nt) {
            half8 b = *(const half8*)(Bp + (size_t)nt * 16 * K + ks * 32);
            acc[nt] = __builtin_amdgcn_mfma_f32_16x16x32_f16(b, a, acc[nt], 0, 0, 0);
        }
    }

    if (rowv < M) {
#pragma unroll
        for (int nt = 0; nt < NT; ++nt) {
            half4v cv = {(_Float16)acc[nt][0], (_Float16)acc[nt][1],
                         (_Float16)acc[nt][2], (_Float16)acc[nt][3]};
            *(half4v*)(C + (size_t)rowv * N + nt * 16 + lk * 4) = cv;
        }
    }

    constexpr int TPH = NT / HEADS;
#pragma unroll
    for (int hh = 0; hh < HEADS; ++hh) {
        float ps = 0.f, pd = 0.f;
#pragma unroll
        for (int q = 0; q < TPH; ++q) {
            int nt = hh * TPH + q;
            float4 s4 = *(const float4*)(atts + nt * 16 + lk * 4);
            float4 d4 = *(const float4*)(attd + nt * 16 + lk * 4);
            ps += acc[nt][0] * s4.x + acc[nt][1] * s4.y + acc[nt][2] * s4.z + acc[nt][3] * s4.w;
            pd += acc[nt][0] * d4.x + acc[nt][1] * d4.y + acc[nt][2] * d4.z + acc[nt][3] * d4.w;
        }
        ps += __shfl_xor(ps, 16); ps += __shfl_xor(ps, 32);
        pd += __shfl_xor(pd, 16); pd += __shfl_xor(pd, 32);
        if (l < 16 && rowv < M) {
            asT[(size_t)hh * M + rowv] = ps;            // transposed
            ad_[(size_t)rowv * HEADS + hh] = pd;
        }
    }
}

// ---------------- layer-1 aggregation: XCD-affine work-stealing, head-sliced ----------------
// 8*(N/4) blocks; each claims one (head, 4-node chunk). Blocks prefer their own
// XCD's head queue (true id via s_getreg), steal otherwise -> correctness never
// depends on the mapping. Per-head working set: 3.2MB h1-slice + 200KB asT row.
// Inner loop identical to r7's correctness-verified slice loop.

__global__ __launch_bounds__(256) void agg1_kernel(const int* __restrict__ offs,
                                                   const int* __restrict__ esrc,
                                                   const float* __restrict__ asT,
                                                   const float* __restrict__ ad_,
                                                   const _Float16* __restrict__ h,
                                                   const float* __restrict__ bias,
                                                   _Float16* __restrict__ o1h,
                                                   int* __restrict__ qctr,
                                                   int nchunks, int N) {
    __shared__ int s_head, s_chunk;
    if (threadIdx.x == 0) {
        int x = xcc_id();
        int head = -1, chunk = -1;
        for (int tq = 0; tq < 8; ++tq) {
            int q = (x + tq) & 7;
            int c = atomicAdd(&qctr[q], 1);
            if (c < nchunks) { head = q; chunk = c; break; }
        }
        s_head = head; s_chunk = chunk;
    }
    __syncthreads();
    int hh = s_head;
    if (hh < 0) return;                 // all queues drained (can't happen: #blocks==#items)
    int n = s_chunk * 4 + (threadIdx.x >> 6);
    int l = threadIdx.x & 63;
    int beg = offs[n], deg = offs[n + 1] - beg;
    float adh = ad_[n * 8 + hh];
    const float* asrow = asT + (size_t)hh * N;
    int slot8 = l >> 3, cq = l & 7;     // 8 edge slots x 8 lanes (4 ch each)

    float ex_c = 0.f; int s_c = 0;
    if (l < deg) {
        s_c = esrc[beg + l];
        float e = asrow[s_c] + adh;
        e = (e > 0.f) ? e : NEG * e;
        ex_c = __expf(e);
    }

    float acc[4] = {0.f, 0.f, 0.f, 0.f};
    float dsum = 0.f;
    for (int cs = 0; cs < deg; cs += 64) {
        float ex_n = 0.f; int s_n = 0;
        int inext = cs + 64 + l;
        if (inext < deg) {
            s_n = esrc[beg + inext];
            float e = asrow[s_n] + adh;
            e = (e > 0.f) ? e : NEG * e;
            ex_n = __expf(e);
        }
        dsum += ex_c;
        int lim = deg - cs; if (lim > 64) lim = 64;
        int gmax = (lim + 7) >> 3;                  // wave-uniform
        for (int g = 0; g < gmax; ++g) {
            int sid = g * 8 + slot8;
            int s2 = __shfl(s_c, sid);              // all lanes execute
            float wgt = __shfl(ex_c, sid);
            if (sid < lim) {
                half4v hv = *(const half4v*)(h + (size_t)s2 * HH + hh * 32 + cq * 4);
#pragma unroll
                for (int q = 0; q < 4; ++q) acc[q] += wgt * (float)hv[q];
            }
        }
        ex_c = ex_n; s_c = s_n;
    }
#pragma unroll
    for (int q = 0; q < 4; ++q) {
        acc[q] += __shfl_xor(acc[q], 8);
        acc[q] += __shfl_xor(acc[q], 16);
        acc[q] += __shfl_xor(acc[q], 32);
    }
    dsum += __shfl_xor(dsum, 1); dsum += __shfl_xor(dsum, 2); dsum += __shfl_xor(dsum, 4);
    dsum += __shfl_xor(dsum, 8); dsum += __shfl_xor(dsum, 16); dsum += __shfl_xor(dsum, 32);
    float inv = 1.f / (dsum + 1e-16f);
    if (l < 8) {
        int c0 = hh * 32 + cq * 4;
        half4v o;
#pragma unroll
        for (int q = 0; q < 4; ++q) {
            float v = acc[q] * inv + bias[c0 + q];
            o[q] = (_Float16)fmaxf(v, 0.f);     // bias + ReLU fused
        }
        *(half4v*)(o1h + (size_t)n * HH + c0) = o;
    }
}

// ---------------- layer-2 aggregation: 16B/lane gathers (r8/r9-proven) ----------------

__global__ __launch_bounds__(256) void agg2_kernel(const int* __restrict__ offs,
                                                   const int* __restrict__ esrc,
                                                   const float* __restrict__ as_,
                                                   const float* __restrict__ ad_,
                                                   const _Float16* __restrict__ h,
                                                   const float* __restrict__ bias,
                                                   float* __restrict__ out) {
    int n = blockIdx.x * 4 + (threadIdx.x >> 6);
    int l = threadIdx.x & 63;
    int beg = offs[n], deg = offs[n + 1] - beg;
    float adn = ad_[n];
    int slot8 = l >> 3;
    int cq = l & 7;

    float ex_c = 0.f; int s_c = 0;
    if (l < deg) {
        s_c = esrc[beg + l];
        float e = as_[s_c] + adn;
        e = (e > 0.f) ? e : NEG * e;
        ex_c = __expf(e);
    }

    float acc[8] = {0.f, 0.f, 0.f, 0.f, 0.f, 0.f, 0.f, 0.f};
    float dsum = 0.f;
    for (int cs = 0; cs < deg; cs += 64) {
        float ex_n = 0.f; int s_n = 0;
        int inext = cs + 64 + l;
        if (inext < deg) {
            s_n = esrc[beg + inext];
            float e = as_[s_n] + adn;
            e = (e > 0.f) ? e : NEG * e;
            ex_n = __expf(e);
        }
        dsum += ex_c;
        int lim = deg - cs; if (lim > 64) lim = 64;
        if (lim >= 64) {
#pragma unroll
            for (int g = 0; g < 8; ++g) {
                int slot = g * 8 + slot8;
                int s2 = __shfl(s_c, slot);
                float wgt = __shfl(ex_c, slot);
                half8 hv = *(const half8*)(h + (size_t)s2 * OUTC + cq * 8);
#pragma unroll
                for (int q = 0; q < 8; ++q) acc[q] += wgt * (float)hv[q];
            }
        } else {
            int gmax = (lim + 7) >> 3;              // wave-uniform
            for (int g = 0; g < gmax; ++g) {
                int slot = g * 8 + slot8;
                int s2 = __shfl(s_c, slot);         // all lanes execute
                float wgt = __shfl(ex_c, slot);
                if (slot < lim) {
                    half8 hv = *(const half8*)(h + (size_t)s2 * OUTC + cq * 8);
#pragma unroll
                    for (int q = 0; q < 8; ++q) acc[q] += wgt * (float)hv[q];
                }
            }
        }
        ex_c = ex_n; s_c = s_n;
    }
#pragma unroll
    for (int q = 0; q < 8; ++q) {
        acc[q] += __shfl_xor(acc[q], 8);
        acc[q] += __shfl_xor(acc[q], 16);
        acc[q] += __shfl_xor(acc[q], 32);
    }
    dsum += __shfl_xor(dsum, 1); dsum += __shfl_xor(dsum, 2); dsum += __shfl_xor(dsum, 4);
    dsum += __shfl_xor(dsum, 8); dsum += __shfl_xor(dsum, 16); dsum += __shfl_xor(dsum, 32);
    float inv = 1.f / (dsum + 1e-16f);
    if (l < 8) {
        int c0 = l * 8;
        float4 o0, o1;
        o0.x = acc[0] * inv + bias[c0 + 0];
        o0.y = acc[1] * inv + bias[c0 + 1];
        o0.z = acc[2] * inv + bias[c0 + 2];
        o0.w = acc[3] * inv + bias[c0 + 3];
        o1.x = acc[4] * inv + bias[c0 + 4];
        o1.y = acc[5] * inv + bias[c0 + 5];
        o1.z = acc[6] * inv + bias[c0 + 6];
        o1.w = acc[7] * inv + bias[c0 + 7];
        *(float4*)(out + (size_t)n * OUTC + c0) = o0;
        *(float4*)(out + (size_t)n * OUTC + c0 + 4) = o1;
    }
}

// ---------------- launcher ----------------

extern "C" void kernel_launch(void* const* d_in, const int* in_sizes, int n_in,
                              void* d_out, int out_size, void* d_ws, size_t ws_size,
                              hipStream_t stream) {
    const float* x    = (const float*)d_in[0];
    const int*   ei   = (const int*)d_in[1];
    const float* W1   = (const float*)d_in[2];
    const float* as1w = (const float*)d_in[3];
    const float* ad1w = (const float*)d_in[4];
    const float* b1   = (const float*)d_in[5];
    const float* W2   = (const float*)d_in[6];
    const float* as2w = (const float*)d_in[7];
    const float* ad2w = (const float*)d_in[8];
    const float* b2   = (const float*)d_in[9];
    float* out = (float*)d_out;

    int N = in_sizes[0] / 128;
    int E = in_sizes[1] / 2;
    int Etot = E + N;
    int nb = (N + 255) / 256;
    int MB = (N + 63) / 64;
    int nchunks = N / 4;

    char* p = (char*)d_ws;
    auto alloc = [&](size_t bytes) { char* r = p; p += (bytes + 255) & ~(size_t)255; return r; };
    _Float16* h1  = (_Float16*)alloc((size_t)N * HH * 2);
    _Float16* o1h = (_Float16*)alloc((size_t)N * HH * 2);
    _Float16* h2  = (_Float16*)alloc((size_t)N * OUTC * 2);
    _Float16* W1t = (_Float16*)alloc((size_t)128 * HH * 2);
    _Float16* W2t = (_Float16*)alloc((size_t)HH * OUTC * 2);
    float* a_s1 = (float*)alloc((size_t)N * 8 * 4);   // asT1[8][N]
    float* a_d1 = (float*)alloc((size_t)N * 8 * 4);   // ad1[N][8]
    float* a_s2 = (float*)alloc((size_t)N * 4);
    float* a_d2 = (float*)alloc((size_t)N * 4);
    int* deg    = (int*)  alloc((size_t)N * 4);
    int* offs   = (int*)  alloc((size_t)(N + 1) * 4);
    int* cursor = (int*)  alloc((size_t)N * 4);
    int* part   = (int*)  alloc(256 * 4);
    int* qctr   = (int*)  alloc(8 * 4);
    int* esrc   = (int*)  alloc((size_t)Etot * 4);

    // CSR by destination (includes self-loops); weight casts + qctr zero folded in
    hipMemsetAsync(deg, 0, sizeof(int) * N, stream);
    hist_cast<<<(Etot + 255) / 256, 256, 0, stream>>>(ei, E, N, W1, W2, W1t, W2t, deg, qctr);
    scan_block<<<nb, 256, 0, stream>>>(deg, offs, part, N);
    scan_finish<<<nb, 256, 0, stream>>>(offs, cursor, deg, part, N, nb);
    scatter_kernel<<<(Etot + 255) / 256, 256, 0, stream>>>(ei, E, N, cursor, esrc);

    // layer 1: GEMM (scores fused, asT) -> XCD-affine head-sliced aggregate
    mfma_gemm<128, 16, 8, true><<<MB, 256, 0, stream>>>(x, W1t, h1, as1w, ad1w, a_s1, a_d1, N);
    agg1_kernel<<<nchunks * 8, 256, 0, stream>>>(offs, esrc, a_s1, a_d1, h1, b1, o1h,
                                                 qctr, nchunks, N);

    // layer 2
    mfma_gemm<256, 4, 1, false><<<MB, 256, 0, stream>>>(o1h, W2t, h2, as2w, ad2w, a_s2, a_d2, N);
    agg2_kernel<<<N / 4, 256, 0, stream>>>(offs, esrc, a_s2, a_d2, h2, b2, out);
}

// Round 12
// 291.200 us; speedup vs baseline: 4.6825x; 4.6825x over previous
//
#include <hip/hip_runtime.h>
#include <cstddef>

#define HH   256   // HEADS*HID
#define OUTC 64
#define NEG  0.2f

typedef _Float16 half8  __attribute__((ext_vector_type(8)));
typedef _Float16 half4v __attribute__((ext_vector_type(4)));
typedef float    f32x4  __attribute__((ext_vector_type(4)));

// ---------------- CSR build ----------------

// histogram + folded weight transpose/casts
__global__ __launch_bounds__(256) void hist_cast(const int* __restrict__ ei, int E, int N,
                                                 const float* __restrict__ W1,
                                                 const float* __restrict__ W2,
                                                 _Float16* __restrict__ W1t,
                                                 _Float16* __restrict__ W2t,
                                                 int* __restrict__ deg) {
    int i = blockIdx.x * 256 + threadIdx.x;
    int tot = E + N;
    if (i < tot) {
        int dst = (i < E) ? ei[E + i] : (i - E);   // self-loop for i>=E
        atomicAdd(&deg[dst], 1);
    }
    const int n1 = 128 * HH, n2 = HH * OUTC;
    if (i < n1 + n2) {
        if (i < n1) { int nn = i / 128, k = i - nn * 128; W1t[i] = (_Float16)W1[(size_t)k * HH + nn]; }
        else { int j = i - n1; int nn = j / HH, k = j - nn * HH; W2t[j] = (_Float16)W2[(size_t)k * OUTC + nn]; }
    }
}

__global__ __launch_bounds__(256) void scan_block(const int* __restrict__ deg,
                                                  int* __restrict__ offs,
                                                  int* __restrict__ part, int n) {
    __shared__ int sh[256];
    int t = threadIdx.x;
    int i = blockIdx.x * 256 + t;
    int v = (i < n) ? deg[i] : 0;
    sh[t] = v;
    __syncthreads();
    for (int off = 1; off < 256; off <<= 1) {
        int x = (t >= off) ? sh[t - off] : 0;
        __syncthreads();
        sh[t] += x;
        __syncthreads();
    }
    if (i < n) offs[i + 1] = sh[t];
    if (t == 255) part[blockIdx.x] = sh[255];
}

// merged: each block redundantly scans part[] (nb<=256), applies prefix, writes cursor
__global__ __launch_bounds__(256) void scan_finish(int* __restrict__ offs,
                                                   int* __restrict__ cursor,
                                                   const int* __restrict__ deg,
                                                   const int* __restrict__ part,
                                                   int n, int nb) {
    __shared__ int sh[256];
    int t = threadIdx.x, bid = blockIdx.x;
    sh[t] = (t < nb) ? part[t] : 0;
    __syncthreads();
    for (int off = 1; off < 256; off <<= 1) {
        int x = (t >= off) ? sh[t - off] : 0;
        __syncthreads();
        sh[t] += x;
        __syncthreads();
    }
    int excl = (bid == 0) ? 0 : sh[bid - 1];
    int i = bid * 256 + t;
    if (i < n) {
        int v = offs[i + 1] + excl;
        offs[i + 1] = v;
        cursor[i] = v - deg[i];
    }
    if (i == 0) offs[0] = 0;
}

__global__ __launch_bounds__(256) void scatter_kernel(const int* __restrict__ ei, int E, int N,
                                                      int* __restrict__ cursor,
                                                      int* __restrict__ esrc) {
    int i = blockIdx.x * blockDim.x + threadIdx.x;
    int tot = E + N;
    if (i >= tot) return;
    int src, dst;
    if (i < E) { src = ei[i]; dst = ei[E + i]; }
    else       { src = dst = i - E; }
    int pos = atomicAdd(&cursor[dst], 1);
    esrc[pos] = src;
}

// ---------------- MFMA fp16 GEMM (swapped operands, fused score epilogue, r8-proven) ----------------

template <int K, int NT, int HEADS, bool AF32>
__global__ __launch_bounds__(256) void mfma_gemm(const void* __restrict__ Av,
                                                 const _Float16* __restrict__ Bt,
                                                 _Float16* __restrict__ C,
                                                 const float* __restrict__ atts,
                                                 const float* __restrict__ attd,
                                                 float* __restrict__ as_,
                                                 float* __restrict__ ad_,
                                                 int M) {
    constexpr int N = NT * 16;
    int t = threadIdx.x;
    int w = t >> 6, l = t & 63;
    int lm = l & 15, lk = l >> 4;
    int row0 = blockIdx.x * 64 + w * 16;
    int rowv = row0 + lm;
    int rA = rowv; if (rA >= M) rA = M - 1;
    int kOff = lk * 8;

    f32x4 acc[NT];
#pragma unroll
    for (int i = 0; i < NT; ++i) acc[i] = (f32x4){0.f, 0.f, 0.f, 0.f};

    const float*    Af = (const float*)Av    + (size_t)rA * K + kOff;
    const _Float16* Ah = (const _Float16*)Av + (size_t)rA * K + kOff;
    const _Float16* Bp = Bt + (size_t)lm * K + kOff;

#pragma unroll 1
    for (int ks = 0; ks < K / 32; ++ks) {
        half8 a;
        if constexpr (AF32) {
            float4 a0 = *(const float4*)(Af + ks * 32);
            float4 a1 = *(const float4*)(Af + ks * 32 + 4);
            a = (half8){(_Float16)a0.x, (_Float16)a0.y, (_Float16)a0.z, (_Float16)a0.w,
                        (_Float16)a1.x, (_Float16)a1.y, (_Float16)a1.z, (_Float16)a1.w};
        } else {
            a = *(const half8*)(Ah + ks * 32);
        }
#pragma unroll
        for (int nt = 0; nt < NT; ++nt) {
            half8 b = *(const half8*)(Bp + (size_t)nt * 16 * K + ks * 32);
            acc[nt] = __builtin_amdgcn_mfma_f32_16x16x32_f16(b, a, acc[nt], 0, 0, 0);
        }
    }

    if (rowv < M) {
#pragma unroll
        for (int nt = 0; nt < NT; ++nt) {
            half4v cv = {(_Float16)acc[nt][0], (_Float16)acc[nt][1],
                         (_Float16)acc[nt][2], (_Float16)acc[nt][3]};
            *(half4v*)(C + (size_t)rowv * N + nt * 16 + lk * 4) = cv;
        }
    }

    constexpr int TPH = NT / HEADS;
#pragma unroll
    for (int hh = 0; hh < HEADS; ++hh) {
        float ps = 0.f, pd = 0.f;
#pragma unroll
        for (int q = 0; q < TPH; ++q) {
            int nt = hh * TPH + q;
            float4 s4 = *(const float4*)(atts + nt * 16 + lk * 4);
            float4 d4 = *(const float4*)(attd + nt * 16 + lk * 4);
            ps += acc[nt][0] * s4.x + acc[nt][1] * s4.y + acc[nt][2] * s4.z + acc[nt][3] * s4.w;
            pd += acc[nt][0] * d4.x + acc[nt][1] * d4.y + acc[nt][2] * d4.z + acc[nt][3] * d4.w;
        }
        ps += __shfl_xor(ps, 16); ps += __shfl_xor(ps, 32);
        pd += __shfl_xor(pd, 16); pd += __shfl_xor(pd, 32);
        if (l < 16 && rowv < M) {
            as_[(size_t)rowv * HEADS + hh] = ps;
            ad_[(size_t)rowv * HEADS + hh] = pd;
        }
    }
}

// ---------------- layer-1 aggregation: TWO TEMPORAL PASSES over channel halves ----------------
// Pass p handles heads p*4..p*4+3 (channels p*128..+127): per-pass gather footprint
// 12.8MB (other half never touched). 16-edge chunks; 4 row-groups x 16 lanes x 16B.
// All shfls unconditional with wave-uniform trip counts (r3/r4 lesson).

template <int PASS>
__global__ __launch_bounds__(256) void agg1_pass(const int* __restrict__ offs,
                                                 const int* __restrict__ esrc,
                                                 const float* __restrict__ as_,
                                                 const float* __restrict__ ad_,
                                                 const _Float16* __restrict__ h,
                                                 const float* __restrict__ bias,
                                                 _Float16* __restrict__ o1h) {
    constexpr int HB = PASS * 4;        // head base
    constexpr int CB = PASS * 128;      // channel base
    int n = blockIdx.x * 4 + (threadIdx.x >> 6);
    int l = threadIdx.x & 63;
    int beg = offs[n], deg = offs[n + 1] - beg;
    int hA = l & 3;          // score head offset 0..3
    int j  = l >> 2;         // score slot 0..15
    int cq = l & 15;         // gather: 16B piece (channels CB+cq*8..+7)
    int rq = l >> 4;         // gather: row group 0..3
    int hW = cq >> 2;        // head offset owning lane's channels
    float adh = ad_[n * 8 + HB + hA];

    // scores for chunk 0 (16 edges)
    float ex_c = 0.f; int s_c = 0;
    if (j < deg) {
        s_c = esrc[beg + j];
        float e = as_[s_c * 8 + HB + hA] + adh;
        e = (e > 0.f) ? e : NEG * e;
        ex_c = __expf(e);
    }

    float acc[8] = {0.f, 0.f, 0.f, 0.f, 0.f, 0.f, 0.f, 0.f};
    float dsum = 0.f;
    for (int cs = 0; cs < deg; cs += 16) {
        // prefetch next chunk's scores
        float ex_n = 0.f; int s_n = 0;
        int inext = cs + 16 + j;
        if (inext < deg) {
            s_n = esrc[beg + inext];
            float e = as_[s_n * 8 + HB + hA] + adh;
            e = (e > 0.f) ? e : NEG * e;
            ex_n = __expf(e);
        }
        dsum += ex_c;
        int lim = deg - cs;
        if (lim >= 16) {
#pragma unroll
            for (int it = 0; it < 4; ++it) {
                int slot = it * 4 + rq;
                int s2 = __shfl(s_c, slot * 4);
                float wgt = __shfl(ex_c, slot * 4 + hW);
                half8 hv = *(const half8*)(h + (size_t)s2 * HH + CB + cq * 8);
#pragma unroll
                for (int q = 0; q < 8; ++q) acc[q] += wgt * (float)hv[q];
            }
        } else {
            int itmax = (lim + 3) >> 2;             // wave-uniform
            for (int it = 0; it < itmax; ++it) {
                int slot = it * 4 + rq;
                int s2 = __shfl(s_c, slot * 4);     // all lanes execute
                float wgt = __shfl(ex_c, slot * 4 + hW);
                if (slot < lim) {
                    half8 hv = *(const half8*)(h + (size_t)s2 * HH + CB + cq * 8);
#pragma unroll
                    for (int q = 0; q < 8; ++q) acc[q] += wgt * (float)hv[q];
                }
            }
        }
        ex_c = ex_n; s_c = s_n;
    }
    // reduce acc across the 4 row groups (lanes sharing cq)
#pragma unroll
    for (int q = 0; q < 8; ++q) {
        acc[q] += __shfl_xor(acc[q], 16);
        acc[q] += __shfl_xor(acc[q], 32);
    }
    // dsum: sum over slots (bits 2..5) -> every lane holds its head (l&3)'s denom
    dsum += __shfl_xor(dsum, 4); dsum += __shfl_xor(dsum, 8);
    dsum += __shfl_xor(dsum, 16); dsum += __shfl_xor(dsum, 32);
    float denom = __shfl(dsum, hW);     // lane hW holds head hW's denom
    float inv = 1.f / (denom + 1e-16f);
    if (l < 16) {
        half8 o;
#pragma unroll
        for (int q = 0; q < 8; ++q) {
            float v = acc[q] * inv + bias[CB + cq * 8 + q];
            o[q] = (_Float16)fmaxf(v, 0.f);     // bias + ReLU fused, fp16 out
        }
        *(half8*)(o1h + (size_t)n * HH + CB + cq * 8) = o;
    }
}

// ---------------- layer-2 aggregation: 16B/lane gathers (r9/r10-proven) ----------------

__global__ __launch_bounds__(256) void agg2_kernel(const int* __restrict__ offs,
                                                   const int* __restrict__ esrc,
                                                   const float* __restrict__ as_,
                                                   const float* __restrict__ ad_,
                                                   const _Float16* __restrict__ h,
                                                   const float* __restrict__ bias,
                                                   float* __restrict__ out) {
    int n = blockIdx.x * 4 + (threadIdx.x >> 6);
    int l = threadIdx.x & 63;
    int beg = offs[n], deg = offs[n + 1] - beg;
    float adn = ad_[n];
    int slot8 = l >> 3;
    int cq = l & 7;

    float ex_c = 0.f; int s_c = 0;
    if (l < deg) {
        s_c = esrc[beg + l];
        float e = as_[s_c] + adn;
        e = (e > 0.f) ? e : NEG * e;
        ex_c = __expf(e);
    }

    float acc[8] = {0.f, 0.f, 0.f, 0.f, 0.f, 0.f, 0.f, 0.f};
    float dsum = 0.f;
    for (int cs = 0; cs < deg; cs += 64) {
        float ex_n = 0.f; int s_n = 0;
        int inext = cs + 64 + l;
        if (inext < deg) {
            s_n = esrc[beg + inext];
            float e = as_[s_n] + adn;
            e = (e > 0.f) ? e : NEG * e;
            ex_n = __expf(e);
        }
        dsum += ex_c;
        int lim = deg - cs; if (lim > 64) lim = 64;
        if (lim >= 64) {
#pragma unroll
            for (int g = 0; g < 8; ++g) {
                int slot = g * 8 + slot8;
                int s2 = __shfl(s_c, slot);
                float wgt = __shfl(ex_c, slot);
                half8 hv = *(const half8*)(h + (size_t)s2 * OUTC + cq * 8);
#pragma unroll
                for (int q = 0; q < 8; ++q) acc[q] += wgt * (float)hv[q];
            }
        } else {
            int gmax = (lim + 7) >> 3;              // wave-uniform
            for (int g = 0; g < gmax; ++g) {
                int slot = g * 8 + slot8;
                int s2 = __shfl(s_c, slot);         // all lanes execute
                float wgt = __shfl(ex_c, slot);
                if (slot < lim) {
                    half8 hv = *(const half8*)(h + (size_t)s2 * OUTC + cq * 8);
#pragma unroll
                    for (int q = 0; q < 8; ++q) acc[q] += wgt * (float)hv[q];
                }
            }
        }
        ex_c = ex_n; s_c = s_n;
    }
#pragma unroll
    for (int q = 0; q < 8; ++q) {
        acc[q] += __shfl_xor(acc[q], 8);
        acc[q] += __shfl_xor(acc[q], 16);
        acc[q] += __shfl_xor(acc[q], 32);
    }
    dsum += __shfl_xor(dsum, 1); dsum += __shfl_xor(dsum, 2); dsum += __shfl_xor(dsum, 4);
    dsum += __shfl_xor(dsum, 8); dsum += __shfl_xor(dsum, 16); dsum += __shfl_xor(dsum, 32);
    float inv = 1.f / (dsum + 1e-16f);
    if (l < 8) {
        int c0 = l * 8;
        float4 o0, o1;
        o0.x = acc[0] * inv + bias[c0 + 0];
        o0.y = acc[1] * inv + bias[c0 + 1];
        o0.z = acc[2] * inv + bias[c0 + 2];
        o0.w = acc[3] * inv + bias[c0 + 3];
        o1.x = acc[4] * inv + bias[c0 + 4];
        o1.y = acc[5] * inv + bias[c0 + 5];
        o1.z = acc[6] * inv + bias[c0 + 6];
        o1.w = acc[7] * inv + bias[c0 + 7];
        *(float4*)(out + (size_t)n * OUTC + c0) = o0;
        *(float4*)(out + (size_t)n * OUTC + c0 + 4) = o1;
    }
}

// ---------------- launcher ----------------

extern "C" void kernel_launch(void* const* d_in, const int* in_sizes, int n_in,
                              void* d_out, int out_size, void* d_ws, size_t ws_size,
                              hipStream_t stream) {
    const float* x    = (const float*)d_in[0];
    const int*   ei   = (const int*)d_in[1];
    const float* W1   = (const float*)d_in[2];
    const float* as1w = (const float*)d_in[3];
    const float* ad1w = (const float*)d_in[4];
    const float* b1   = (const float*)d_in[5];
    const float* W2   = (const float*)d_in[6];
    const float* as2w = (const float*)d_in[7];
    const float* ad2w = (const float*)d_in[8];
    const float* b2   = (const float*)d_in[9];
    float* out = (float*)d_out;

    int N = in_sizes[0] / 128;
    int E = in_sizes[1] / 2;
    int Etot = E + N;
    int nb = (N + 255) / 256;
    int MB = (N + 63) / 64;

    char* p = (char*)d_ws;
    auto alloc = [&](size_t bytes) { char* r = p; p += (bytes + 255) & ~(size_t)255; return r; };
    _Float16* h1  = (_Float16*)alloc((size_t)N * HH * 2);
    _Float16* o1h = (_Float16*)alloc((size_t)N * HH * 2);
    _Float16* h2  = (_Float16*)alloc((size_t)N * OUTC * 2);
    _Float16* W1t = (_Float16*)alloc((size_t)128 * HH * 2);
    _Float16* W2t = (_Float16*)alloc((size_t)HH * OUTC * 2);
    float* a_s1 = (float*)alloc((size_t)N * 8 * 4);
    float* a_d1 = (float*)alloc((size_t)N * 8 * 4);
    float* a_s2 = (float*)alloc((size_t)N * 4);
    float* a_d2 = (float*)alloc((size_t)N * 4);
    int* deg    = (int*)  alloc((size_t)N * 4);
    int* offs   = (int*)  alloc((size_t)(N + 1) * 4);
    int* cursor = (int*)  alloc((size_t)N * 4);
    int* part   = (int*)  alloc(256 * 4);
    int* esrc   = (int*)  alloc((size_t)Etot * 4);

    // CSR by destination (includes self-loops); weight casts folded into hist
    hipMemsetAsync(deg, 0, sizeof(int) * N, stream);
    hist_cast<<<(Etot + 255) / 256, 256, 0, stream>>>(ei, E, N, W1, W2, W1t, W2t, deg);
    scan_block<<<nb, 256, 0, stream>>>(deg, offs, part, N);
    scan_finish<<<nb, 256, 0, stream>>>(offs, cursor, deg, part, N, nb);
    scatter_kernel<<<(Etot + 255) / 256, 256, 0, stream>>>(ei, E, N, cursor, esrc);

    // layer 1: GEMM (scores fused) -> two temporal channel-half passes
    mfma_gemm<128, 16, 8, true><<<MB, 256, 0, stream>>>(x, W1t, h1, as1w, ad1w, a_s1, a_d1, N);
    agg1_pass<0><<<N / 4, 256, 0, stream>>>(offs, esrc, a_s1, a_d1, h1, b1, o1h);
    agg1_pass<1><<<N / 4, 256, 0, stream>>>(offs, esrc, a_s1, a_d1, h1, b1, o1h);

    // layer 2
    mfma_gemm<256, 4, 1, false><<<MB, 256, 0, stream>>>(o1h, W2t, h2, as2w, ad2w, a_s2, a_d2, N);
    agg2_kernel<<<N / 4, 256, 0, stream>>>(offs, esrc, a_s2, a_d2, h2, b2, out);
}

// Round 13
// 263.578 us; speedup vs baseline: 5.1732x; 1.1048x over previous
//
#include <hip/hip_runtime.h>
#include <cstddef>

#define HH   256   // HEADS*HID
#define OUTC 64
#define NEG  0.2f

typedef _Float16 half8  __attribute__((ext_vector_type(8)));
typedef _Float16 half4v __attribute__((ext_vector_type(4)));
typedef float    f32x4  __attribute__((ext_vector_type(4)));
typedef unsigned short u16;

// ---------------- CSR build ----------------

// histogram + folded weight transpose/casts
__global__ __launch_bounds__(256) void hist_cast(const int* __restrict__ ei, int E, int N,
                                                 const float* __restrict__ W1,
                                                 const float* __restrict__ W2,
                                                 _Float16* __restrict__ W1t,
                                                 _Float16* __restrict__ W2t,
                                                 int* __restrict__ deg) {
    int i = blockIdx.x * 256 + threadIdx.x;
    int tot = E + N;
    if (i < tot) {
        int dst = (i < E) ? ei[E + i] : (i - E);   // self-loop for i>=E
        atomicAdd(&deg[dst], 1);
    }
    const int n1 = 128 * HH, n2 = HH * OUTC;
    if (i < n1 + n2) {
        if (i < n1) { int nn = i / 128, k = i - nn * 128; W1t[i] = (_Float16)W1[(size_t)k * HH + nn]; }
        else { int j = i - n1; int nn = j / HH, k = j - nn * HH; W2t[j] = (_Float16)W2[(size_t)k * OUTC + nn]; }
    }
}

__global__ __launch_bounds__(256) void scan_block(const int* __restrict__ deg,
                                                  int* __restrict__ offs,
                                                  int* __restrict__ part, int n) {
    __shared__ int sh[256];
    int t = threadIdx.x;
    int i = blockIdx.x * 256 + t;
    int v = (i < n) ? deg[i] : 0;
    sh[t] = v;
    __syncthreads();
    for (int off = 1; off < 256; off <<= 1) {
        int x = (t >= off) ? sh[t - off] : 0;
        __syncthreads();
        sh[t] += x;
        __syncthreads();
    }
    if (i < n) offs[i + 1] = sh[t];
    if (t == 255) part[blockIdx.x] = sh[255];
}

// merged: each block redundantly scans part[] (nb<=256), applies prefix, writes cursor
__global__ __launch_bounds__(256) void scan_finish(int* __restrict__ offs,
                                                   int* __restrict__ cursor,
                                                   const int* __restrict__ deg,
                                                   const int* __restrict__ part,
                                                   int n, int nb) {
    __shared__ int sh[256];
    int t = threadIdx.x, bid = blockIdx.x;
    sh[t] = (t < nb) ? part[t] : 0;
    __syncthreads();
    for (int off = 1; off < 256; off <<= 1) {
        int x = (t >= off) ? sh[t - off] : 0;
        __syncthreads();
        sh[t] += x;
        __syncthreads();
    }
    int excl = (bid == 0) ? 0 : sh[bid - 1];
    int i = bid * 256 + t;
    if (i < n) {
        int v = offs[i + 1] + excl;
        offs[i + 1] = v;
        cursor[i] = v - deg[i];
    }
    if (i == 0) offs[0] = 0;
}

// ---------------- FUSED: GEMM1 (MFMA, scores fused) || edge scatter ----------------
// Blocks [0,MB): layer-1 GEMM (r8-proven body). Blocks [MB,..): scatter edges
// into u16 CSR (independent work, hidden under each other).

__global__ __launch_bounds__(256) void gemm1_scatter(const float* __restrict__ A,
                                                     const _Float16* __restrict__ Bt,
                                                     _Float16* __restrict__ C,
                                                     const float* __restrict__ atts,
                                                     const float* __restrict__ attd,
                                                     float* __restrict__ as_,
                                                     float* __restrict__ ad_,
                                                     int M, int MB,
                                                     const int* __restrict__ ei, int E,
                                                     int* __restrict__ cursor,
                                                     u16* __restrict__ esrc) {
    constexpr int K = 128, NT = 16, HEADS = 8;
    constexpr int N = NT * 16;
    int bid = blockIdx.x;

    if (bid >= MB) {
        // ---- scatter part ----
        int i = (bid - MB) * 256 + threadIdx.x;
        int tot = E + M;
        if (i < tot) {
            int src, dst;
            if (i < E) { src = ei[i]; dst = ei[E + i]; }
            else       { src = dst = i - E; }
            int pos = atomicAdd(&cursor[dst], 1);
            esrc[pos] = (u16)src;
        }
        return;
    }

    // ---- GEMM part (r8-proven) ----
    int t = threadIdx.x;
    int w = t >> 6, l = t & 63;
    int lm = l & 15, lk = l >> 4;
    int row0 = bid * 64 + w * 16;
    int rowv = row0 + lm;
    int rA = rowv; if (rA >= M) rA = M - 1;
    int kOff = lk * 8;

    f32x4 acc[NT];
#pragma unroll
    for (int i = 0; i < NT; ++i) acc[i] = (f32x4){0.f, 0.f, 0.f, 0.f};

    const float*    Af = A + (size_t)rA * K + kOff;
    const _Float16* Bp = Bt + (size_t)lm * K + kOff;

#pragma unroll 1
    for (int ks = 0; ks < K / 32; ++ks) {
        float4 a0 = *(const float4*)(Af + ks * 32);
        float4 a1 = *(const float4*)(Af + ks * 32 + 4);
        half8 a = (half8){(_Float16)a0.x, (_Float16)a0.y, (_Float16)a0.z, (_Float16)a0.w,
                          (_Float16)a1.x, (_Float16)a1.y, (_Float16)a1.z, (_Float16)a1.w};
#pragma unroll
        for (int nt = 0; nt < NT; ++nt) {
            half8 b = *(const half8*)(Bp + (size_t)nt * 16 * K + ks * 32);
            acc[nt] = __builtin_amdgcn_mfma_f32_16x16x32_f16(b, a, acc[nt], 0, 0, 0);
        }
    }

    if (rowv < M) {
#pragma unroll
        for (int nt = 0; nt < NT; ++nt) {
            half4v cv = {(_Float16)acc[nt][0], (_Float16)acc[nt][1],
                         (_Float16)acc[nt][2], (_Float16)acc[nt][3]};
            *(half4v*)(C + (size_t)rowv * N + nt * 16 + lk * 4) = cv;
        }
    }

    constexpr int TPH = NT / HEADS;
#pragma unroll
    for (int hh = 0; hh < HEADS; ++hh) {
        float ps = 0.f, pd = 0.f;
#pragma unroll
        for (int q = 0; q < TPH; ++q) {
            int nt = hh * TPH + q;
            float4 s4 = *(const float4*)(atts + nt * 16 + lk * 4);
            float4 d4 = *(const float4*)(attd + nt * 16 + lk * 4);
            ps += acc[nt][0] * s4.x + acc[nt][1] * s4.y + acc[nt][2] * s4.z + acc[nt][3] * s4.w;
            pd += acc[nt][0] * d4.x + acc[nt][1] * d4.y + acc[nt][2] * d4.z + acc[nt][3] * d4.w;
        }
        ps += __shfl_xor(ps, 16); ps += __shfl_xor(ps, 32);
        pd += __shfl_xor(pd, 16); pd += __shfl_xor(pd, 32);
        if (l < 16 && rowv < M) {
            as_[(size_t)rowv * HEADS + hh] = ps;
            ad_[(size_t)rowv * HEADS + hh] = pd;
        }
    }
}

// ---------------- MFMA fp16 GEMM for layer 2 (r8-proven) ----------------

template <int K, int NT, int HEADS>
__global__ __launch_bounds__(256) void mfma_gemm(const _Float16* __restrict__ Ah_,
                                                 const _Float16* __restrict__ Bt,
                                                 _Float16* __restrict__ C,
                                                 const float* __restrict__ atts,
                                                 const float* __restrict__ attd,
                                                 float* __restrict__ as_,
                                                 float* __restrict__ ad_,
                                                 int M) {
    constexpr int N = NT * 16;
    int t = threadIdx.x;
    int w = t >> 6, l = t & 63;
    int lm = l & 15, lk = l >> 4;
    int row0 = blockIdx.x * 64 + w * 16;
    int rowv = row0 + lm;
    int rA = rowv; if (rA >= M) rA = M - 1;
    int kOff = lk * 8;

    f32x4 acc[NT];
#pragma unroll
    for (int i = 0; i < NT; ++i) acc[i] = (f32x4){0.f, 0.f, 0.f, 0.f};

    const _Float16* Ah = Ah_ + (size_t)rA * K + kOff;
    const _Float16* Bp = Bt + (size_t)lm * K + kOff;

#pragma unroll 1
    for (int ks = 0; ks < K / 32; ++ks) {
        half8 a = *(const half8*)(Ah + ks * 32);
#pragma unroll
        for (int nt = 0; nt < NT; ++nt) {
            half8 b = *(const half8*)(Bp + (size_t)nt * 16 * K + ks * 32);
            acc[nt] = __builtin_amdgcn_mfma_f32_16x16x32_f16(b, a, acc[nt], 0, 0, 0);
        }
    }

    if (rowv < M) {
#pragma unroll
        for (int nt = 0; nt < NT; ++nt) {
            half4v cv = {(_Float16)acc[nt][0], (_Float16)acc[nt][1],
                         (_Float16)acc[nt][2], (_Float16)acc[nt][3]};
            *(half4v*)(C + (size_t)rowv * N + nt * 16 + lk * 4) = cv;
        }
    }

    constexpr int TPH = NT / HEADS;
#pragma unroll
    for (int hh = 0; hh < HEADS; ++hh) {
        float ps = 0.f, pd = 0.f;
#pragma unroll
        for (int q = 0; q < TPH; ++q) {
            int nt = hh * TPH + q;
            float4 s4 = *(const float4*)(atts + nt * 16 + lk * 4);
            float4 d4 = *(const float4*)(attd + nt * 16 + lk * 4);
            ps += acc[nt][0] * s4.x + acc[nt][1] * s4.y + acc[nt][2] * s4.z + acc[nt][3] * s4.w;
            pd += acc[nt][0] * d4.x + acc[nt][1] * d4.y + acc[nt][2] * d4.z + acc[nt][3] * d4.w;
        }
        ps += __shfl_xor(ps, 16); ps += __shfl_xor(ps, 32);
        pd += __shfl_xor(pd, 16); pd += __shfl_xor(pd, 32);
        if (l < 16 && rowv < M) {
            as_[(size_t)rowv * HEADS + hh] = ps;
            ad_[(size_t)rowv * HEADS + hh] = pd;
        }
    }
}

// ---------------- layer-1 aggregation (r8-proven shape, u16 esrc) ----------------

__global__ __launch_bounds__(256) void agg1_kernel(const int* __restrict__ offs,
                                                   const u16* __restrict__ esrc,
                                                   const float* __restrict__ as_,
                                                   const float* __restrict__ ad_,
                                                   const _Float16* __restrict__ h,
                                                   const float* __restrict__ bias,
                                                   _Float16* __restrict__ o1h) {
    int n = blockIdx.x * 4 + (threadIdx.x >> 6);
    int l = threadIdx.x & 63;
    int beg = offs[n], deg = offs[n + 1] - beg;
    int hA = l & 7, j = l >> 3;     // score phase: slot j, head hA
    int cg = l & 31;                // channel group: channels cg*8..+7
    int hB = cg >> 2;               // head owning those channels
    int rs = l >> 5;                // row parity (even/odd slots)
    float adh = ad_[n * 8 + hA];

    float ex_c = 0.f; int s_c = 0;
    if (j < deg) {
        s_c = esrc[beg + j];
        float e = as_[s_c * 8 + hA] + adh;
        e = (e > 0.f) ? e : NEG * e;
        ex_c = __expf(e);
    }

    float acc[8] = {0.f, 0.f, 0.f, 0.f, 0.f, 0.f, 0.f, 0.f};
    float dsum = 0.f;
    for (int cs = 0; cs < deg; cs += 8) {
        float ex_n = 0.f; int s_n = 0;
        int inext = cs + 8 + j;
        if (inext < deg) {
            s_n = esrc[beg + inext];
            float e = as_[s_n * 8 + hA] + adh;
            e = (e > 0.f) ? e : NEG * e;
            ex_n = __expf(e);
        }
        dsum += ex_c;
        int lim = deg - cs;
        if (lim >= 8) {
#pragma unroll
            for (int it = 0; it < 4; ++it) {
                int slot = it * 2 + rs;
                int s2 = __shfl(s_c, slot * 8);
                float wgt = __shfl(ex_c, slot * 8 + hB);
                half8 hv = *(const half8*)(h + (size_t)s2 * HH + cg * 8);
#pragma unroll
                for (int q = 0; q < 8; ++q) acc[q] += wgt * (float)hv[q];
            }
        } else {
            int itmax = (lim + 1) >> 1;             // wave-uniform
            for (int it = 0; it < itmax; ++it) {
                int slot = it * 2 + rs;
                int s2 = __shfl(s_c, slot * 8);     // all lanes execute
                float wgt = __shfl(ex_c, slot * 8 + hB);
                if (slot < lim) {
                    half8 hv = *(const half8*)(h + (size_t)s2 * HH + cg * 8);
#pragma unroll
                    for (int q = 0; q < 8; ++q) acc[q] += wgt * (float)hv[q];
                }
            }
        }
        ex_c = ex_n; s_c = s_n;
    }
#pragma unroll
    for (int q = 0; q < 8; ++q) acc[q] += __shfl_xor(acc[q], 32);
    dsum += __shfl_xor(dsum, 8); dsum += __shfl_xor(dsum, 16); dsum += __shfl_xor(dsum, 32);
    float denom = __shfl(dsum, hB);
    float inv = 1.f / (denom + 1e-16f);
    if (l < 32) {
        half8 o;
#pragma unroll
        for (int q = 0; q < 8; ++q) {
            float v = acc[q] * inv + bias[cg * 8 + q];
            o[q] = (_Float16)fmaxf(v, 0.f);     // bias + ReLU fused, fp16 out
        }
        *(half8*)(o1h + (size_t)n * HH + cg * 8) = o;
    }
}

// ---------------- layer-2 aggregation (r9/r10-proven, u16 esrc) ----------------

__global__ __launch_bounds__(256) void agg2_kernel(const int* __restrict__ offs,
                                                   const u16* __restrict__ esrc,
                                                   const float* __restrict__ as_,
                                                   const float* __restrict__ ad_,
                                                   const _Float16* __restrict__ h,
                                                   const float* __restrict__ bias,
                                                   float* __restrict__ out) {
    int n = blockIdx.x * 4 + (threadIdx.x >> 6);
    int l = threadIdx.x & 63;
    int beg = offs[n], deg = offs[n + 1] - beg;
    float adn = ad_[n];
    int slot8 = l >> 3;
    int cq = l & 7;

    float ex_c = 0.f; int s_c = 0;
    if (l < deg) {
        s_c = esrc[beg + l];
        float e = as_[s_c] + adn;
        e = (e > 0.f) ? e : NEG * e;
        ex_c = __expf(e);
    }

    float acc[8] = {0.f, 0.f, 0.f, 0.f, 0.f, 0.f, 0.f, 0.f};
    float dsum = 0.f;
    for (int cs = 0; cs < deg; cs += 64) {
        float ex_n = 0.f; int s_n = 0;
        int inext = cs + 64 + l;
        if (inext < deg) {
            s_n = esrc[beg + inext];
            float e = as_[s_n] + adn;
            e = (e > 0.f) ? e : NEG * e;
            ex_n = __expf(e);
        }
        dsum += ex_c;
        int lim = deg - cs; if (lim > 64) lim = 64;
        if (lim >= 64) {
#pragma unroll
            for (int g = 0; g < 8; ++g) {
                int slot = g * 8 + slot8;
                int s2 = __shfl(s_c, slot);
                float wgt = __shfl(ex_c, slot);
                half8 hv = *(const half8*)(h + (size_t)s2 * OUTC + cq * 8);
#pragma unroll
                for (int q = 0; q < 8; ++q) acc[q] += wgt * (float)hv[q];
            }
        } else {
            int gmax = (lim + 7) >> 3;              // wave-uniform
            for (int g = 0; g < gmax; ++g) {
                int slot = g * 8 + slot8;
                int s2 = __shfl(s_c, slot);         // all lanes execute
                float wgt = __shfl(ex_c, slot);
                if (slot < lim) {
                    half8 hv = *(const half8*)(h + (size_t)s2 * OUTC + cq * 8);
#pragma unroll
                    for (int q = 0; q < 8; ++q) acc[q] += wgt * (float)hv[q];
                }
            }
        }
        ex_c = ex_n; s_c = s_n;
    }
#pragma unroll
    for (int q = 0; q < 8; ++q) {
        acc[q] += __shfl_xor(acc[q], 8);
        acc[q] += __shfl_xor(acc[q], 16);
        acc[q] += __shfl_xor(acc[q], 32);
    }
    dsum += __shfl_xor(dsum, 1); dsum += __shfl_xor(dsum, 2); dsum += __shfl_xor(dsum, 4);
    dsum += __shfl_xor(dsum, 8); dsum += __shfl_xor(dsum, 16); dsum += __shfl_xor(dsum, 32);
    float inv = 1.f / (dsum + 1e-16f);
    if (l < 8) {
        int c0 = l * 8;
        float4 o0, o1;
        o0.x = acc[0] * inv + bias[c0 + 0];
        o0.y = acc[1] * inv + bias[c0 + 1];
        o0.z = acc[2] * inv + bias[c0 + 2];
        o0.w = acc[3] * inv + bias[c0 + 3];
        o1.x = acc[4] * inv + bias[c0 + 4];
        o1.y = acc[5] * inv + bias[c0 + 5];
        o1.z = acc[6] * inv + bias[c0 + 6];
        o1.w = acc[7] * inv + bias[c0 + 7];
        *(float4*)(out + (size_t)n * OUTC + c0) = o0;
        *(float4*)(out + (size_t)n * OUTC + c0 + 4) = o1;
    }
}

// ---------------- launcher ----------------

extern "C" void kernel_launch(void* const* d_in, const int* in_sizes, int n_in,
                              void* d_out, int out_size, void* d_ws, size_t ws_size,
                              hipStream_t stream) {
    const float* x    = (const float*)d_in[0];
    const int*   ei   = (const int*)d_in[1];
    const float* W1   = (const float*)d_in[2];
    const float* as1w = (const float*)d_in[3];
    const float* ad1w = (const float*)d_in[4];
    const float* b1   = (const float*)d_in[5];
    const float* W2   = (const float*)d_in[6];
    const float* as2w = (const float*)d_in[7];
    const float* ad2w = (const float*)d_in[8];
    const float* b2   = (const float*)d_in[9];
    float* out = (float*)d_out;

    int N = in_sizes[0] / 128;
    int E = in_sizes[1] / 2;
    int Etot = E + N;
    int nb = (N + 255) / 256;
    int MB = (N + 63) / 64;
    int nscat = (Etot + 255) / 256;

    char* p = (char*)d_ws;
    auto alloc = [&](size_t bytes) { char* r = p; p += (bytes + 255) & ~(size_t)255; return r; };
    _Float16* h1  = (_Float16*)alloc((size_t)N * HH * 2);
    _Float16* o1h = (_Float16*)alloc((size_t)N * HH * 2);
    _Float16* h2  = (_Float16*)alloc((size_t)N * OUTC * 2);
    _Float16* W1t = (_Float16*)alloc((size_t)128 * HH * 2);
    _Float16* W2t = (_Float16*)alloc((size_t)HH * OUTC * 2);
    float* a_s1 = (float*)alloc((size_t)N * 8 * 4);
    float* a_d1 = (float*)alloc((size_t)N * 8 * 4);
    float* a_s2 = (float*)alloc((size_t)N * 4);
    float* a_d2 = (float*)alloc((size_t)N * 4);
    int* deg    = (int*)  alloc((size_t)N * 4);
    int* offs   = (int*)  alloc((size_t)(N + 1) * 4);
    int* cursor = (int*)  alloc((size_t)N * 4);
    int* part   = (int*)  alloc(256 * 4);
    u16* esrc   = (u16*)  alloc((size_t)Etot * 2);

    // CSR by destination (includes self-loops); weight casts folded into hist
    hipMemsetAsync(deg, 0, sizeof(int) * N, stream);
    hist_cast<<<(Etot + 255) / 256, 256, 0, stream>>>(ei, E, N, W1, W2, W1t, W2t, deg);
    scan_block<<<nb, 256, 0, stream>>>(deg, offs, part, N);
    scan_finish<<<nb, 256, 0, stream>>>(offs, cursor, deg, part, N, nb);

    // fused: layer-1 GEMM (scores fused) || edge scatter (independent work)
    gemm1_scatter<<<MB + nscat, 256, 0, stream>>>(x, W1t, h1, as1w, ad1w, a_s1, a_d1,
                                                  N, MB, ei, E, cursor, esrc);

    agg1_kernel<<<N / 4, 256, 0, stream>>>(offs, esrc, a_s1, a_d1, h1, b1, o1h);

    // layer 2
    mfma_gemm<256, 4, 1><<<MB, 256, 0, stream>>>(o1h, W2t, h2, as2w, ad2w, a_s2, a_d2, N);
    agg2_kernel<<<N / 4, 256, 0, stream>>>(offs, esrc, a_s2, a_d2, h2, b2, out);
}